// Round 9
// baseline (88.455 us; speedup 1.0000x reference)
//
#include <hip/hip_runtime.h>

#define N_ 64
#define C_ 64
#define T_ 256
#define V_ 25
#define R_ 8
#define O_ 64
constexpr int TV = T_ * V_;           // 6400
constexpr float INV_T = 1.0f / (float)T_;
constexpr int TC = 16;                // t's per fused block
constexpr int NPOS = TC * V_;         // 400
constexpr int NT = NPOS / 16;         // 25 MFMA N-tiles
constexpr int DP = 32;                // padded u,v extent of dT in global
constexpr int UPAD = 40;              // u slots per (o,t) row in x3b
constexpr int X3S = 16 * UPAD + 8;    // 648 halfwords per o_local: 1296B stride
                                      //  -> 16B-aligned b128 reads + bank spread

typedef __attribute__((ext_vector_type(8))) short s8v;   // 8 bf16 = 4 VGPR
typedef __attribute__((ext_vector_type(4))) short s4v;   // 4 bf16
typedef __attribute__((ext_vector_type(4))) float f4v;   // MFMA acc

__device__ __forceinline__ unsigned short f2bf(float f) {   // RNE f32->bf16
    union { float f; unsigned u; } v; v.f = f;
    unsigned r = v.u + 0x7FFFu + ((v.u >> 16) & 1u);
    return (unsigned short)(r >> 16);
}

// -------- k_mean: xm[n][c][v] = mean_t x[n][c][t][v]  (proven ~19us, ~85% HBM)
__global__ __launch_bounds__(256) void k_mean(const float* __restrict__ x,
                                              float* __restrict__ xm) {
    __shared__ float part[8 * V_];
    const int bid = blockIdx.x;           // n*C + c
    const int tid = threadIdx.x;
    const float* xp = x + (size_t)bid * TV;
    if (tid < 200) {
        const int vid = tid % V_;
        const int seg = tid / V_;
        float s = 0.f;
        const float* p = xp + seg * 32 * V_ + vid;
        #pragma unroll
        for (int j = 0; j < 32; ++j) s += p[j * V_];
        part[tid] = s;
    }
    __syncthreads();
    if (tid < V_) {
        float s = 0.f;
        #pragma unroll
        for (int k = 0; k < 8; ++k) s += part[k * V_ + tid];
        xm[(size_t)bid * V_ + tid] = s * INV_T;
    }
}

// -------- k_dmat: dT[n][o][v][u] = d(u,v) bf16, zero-padded to 32x32.
__global__ __launch_bounds__(256) void k_dmat(const float* __restrict__ xm,
                                              const float* __restrict__ A,
                                              const float* __restrict__ w1,
                                              const float* __restrict__ b1,
                                              const float* __restrict__ w2,
                                              const float* __restrict__ b2,
                                              const float* __restrict__ w4,
                                              const float* __restrict__ b4,
                                              unsigned short* __restrict__ dT) {
    __shared__ float xms[C_][V_];
    __shared__ float x1s[R_][V_];
    __shared__ float x2s[R_][V_];
    const int n  = blockIdx.x;
    const int og = blockIdx.y * 8;
    const int tid = threadIdx.x;

    for (int i = tid; i < C_ * V_; i += 256)
        xms[i / V_][i % V_] = xm[(size_t)n * C_ * V_ + i];
    __syncthreads();

    for (int i = tid; i < 2 * R_ * V_; i += 256) {
        const int j = i % (R_ * V_);
        const int r = j / V_, v = j % V_;
        const bool first = (i < R_ * V_);
        const float* w = first ? w1 : w2;
        float acc = first ? b1[r] : b2[r];
        #pragma unroll
        for (int c = 0; c < C_; ++c) acc += w[r * C_ + c] * xms[c][v];
        if (first) x1s[r][v] = acc;
        else       x2s[r][v] = acc;
    }
    __syncthreads();

    unsigned short* dn = dT + (size_t)n * O_ * DP * DP;
    for (int p = tid; p < DP * DP; p += 256) {       // p = v*32+u, coalesced in u
        const int v = p >> 5, u = p & 31;
        if (u < V_ && v < V_) {
            float adjr[R_];
            #pragma unroll
            for (int r = 0; r < R_; ++r) adjr[r] = tanhf(x1s[r][u] - x2s[r][v]);
            const float a = A[u * V_ + v];
            #pragma unroll
            for (int oo = 0; oo < 8; ++oo) {
                const int o = og + oo;
                float acc = b4[o];
                #pragma unroll
                for (int r = 0; r < R_; ++r) acc = fmaf(w4[o * R_ + r], adjr[r], acc);
                dn[(size_t)o * DP * DP + p] = f2bf(acc + a);   // ALPHA == 1
            }
        } else {
            #pragma unroll
            for (int oo = 0; oo < 8; ++oo)
                dn[(size_t)(og + oo) * DP * DP + p] = 0;
        }
    }
}

// -------- k_F: stage x->LDS (coalesced float4), GEMM1 (MFMA) per o-quarter
//          into small x3b, GEMM2 (MFMA) per o-quarter. 512 thr, ~72KB LDS ->
//          2 blocks/CU.
__global__ __launch_bounds__(512, 4) void k_F(const float* __restrict__ x,
                                              const float* __restrict__ w3,
                                              const float* __restrict__ b3,
                                              const unsigned short* __restrict__ dT,
                                              float* __restrict__ out) {
    // xs: bf16 x-tile, tile-major [nt][c^swz][16pos]; swizzle c^(pt&7) kills
    //     staging write-bank collisions (pt*2048B is bank-invariant).
    __shared__ __align__(16) unsigned short xs[NT * 1024];        // 51200 B
    __shared__ __align__(16) unsigned short x3b[16 * X3S];        // 20736 B

    const int n    = blockIdx.y;
    const int tc   = blockIdx.x;
    const int tid  = threadIdx.x;
    const int lane = tid & 63;
    const int wave = tid >> 6;      // 0..7
    const int l16  = lane & 15;
    const int lg   = lane >> 4;     // 0..3

    // zero x3b u-pad: GEMM2 reads u in [0,32); GEMM1 writes only u<25, so
    // u in [25,32) must be 0. s8v covers [24,32) (u=24 is rewritten by GEMM1).
    // (Round-8 bug: s4v covered only [24,28) -> u 28..31 were garbage -> NaN.)
    if (tid < 256) {
        const int o_l = tid >> 4, t = tid & 15;
        *(s8v*)&x3b[o_l * X3S + t * UPAD + 24] = (s8v)0;   // 16B-aligned
    }

    // ---- stage x chunk: 6400 float4 slots, coalesced, independent
    {
        const float* xb = x + (size_t)n * C_ * TV + tc * NPOS;
        #pragma unroll 1
        for (int i = 0; i < 13; ++i) {
            const int s = i * 512 + tid;
            if (s < 6400) {
                const int c = s / 100, p4 = s - c * 100;
                const float4 v4 = *(const float4*)(xb + (size_t)c * TV + p4 * 4);
                const int pos = p4 * 4;
                const int pt = pos >> 4;
                s4v pk;
                pk[0] = (short)f2bf(v4.x); pk[1] = (short)f2bf(v4.y);
                pk[2] = (short)f2bf(v4.z); pk[3] = (short)f2bf(v4.w);
                *(s4v*)&xs[pt * 1024 + ((c ^ (pt & 7)) << 4) + (pos & 15)] = pk;
            }
        }
    }
    __syncthreads();

    // ---- hoist this wave's B-frags (reused for all 4 o-quarters)
    s8v bfr[4][2];
    int ts[4], us[4];
    #pragma unroll
    for (int i = 0; i < 4; ++i) {
        const int nt = wave + 8 * i;
        if (nt < NT) {
            const int pos = nt * 16 + l16;
            ts[i] = pos / 25; us[i] = pos - 25 * ts[i];
            const unsigned short* base = &xs[nt * 1024];
            const int sw = nt & 7;
            #pragma unroll
            for (int kh = 0; kh < 2; ++kh) {
                s8v f;
                #pragma unroll
                for (int j = 0; j < 8; ++j) {
                    const int c = kh * 32 + lg * 8 + j;
                    f[j] = (short)base[((c ^ sw) << 4) + l16];   // 2-way max, free
                }
                bfr[i][kh] = f;
            }
        }
    }

    const unsigned short* dn = dT + (size_t)n * O_ * DP * DP;
    float* on = out + (size_t)n * O_ * TV + tc * NPOS;

    #pragma unroll 1
    for (int h = 0; h < 4; ++h) {               // o-quarter: o = h*16 .. h*16+15
        // A-frags for this quarter (w3 L1-resident)
        s8v afr[2];
        #pragma unroll
        for (int kh = 0; kh < 2; ++kh) {
            const float* wp = w3 + (h * 16 + l16) * C_ + kh * 32 + lg * 8;
            s8v f;
            #pragma unroll
            for (int j = 0; j < 8; ++j) f[j] = (short)f2bf(wp[j]);
            afr[kh] = f;
        }
        const f4v b3h = *(const f4v*)(b3 + h * 16 + lg * 4);

        // GEMM1 quarter: x3[o_l][t][u], o_l = lg*4+r
        #pragma unroll
        for (int i = 0; i < 4; ++i) {
            const int nt = wave + 8 * i;
            if (nt < NT) {
                f4v acc = (f4v)0.f;
                acc = __builtin_amdgcn_mfma_f32_16x16x32_bf16(afr[0], bfr[i][0], acc, 0, 0, 0);
                acc = __builtin_amdgcn_mfma_f32_16x16x32_bf16(afr[1], bfr[i][1], acc, 0, 0, 0);
                #pragma unroll
                for (int r = 0; r < 4; ++r)
                    x3b[(lg * 4 + r) * X3S + ts[i] * UPAD + us[i]] = f2bf(acc[r] + b3h[r]);
            }
        }
        __syncthreads();

        // GEMM2 quarter: wave owns o_l = wave*2 + {0,1}
        #pragma unroll
        for (int oo = 0; oo < 2; ++oo) {
            const int o_l = wave * 2 + oo;
            const int o_g = h * 16 + o_l;
            const s8v av  = *(const s8v*)&x3b[o_l * X3S + l16 * UPAD + lg * 8]; // b128
            const unsigned short* dp = dn + (size_t)o_g * DP * DP;
            const s8v bv0 = *(const s8v*)(dp + l16 * DP + lg * 8);
            const s8v bv1 = *(const s8v*)(dp + (16 + l16) * DP + lg * 8);
            f4v c0 = (f4v)0.f, c1 = (f4v)0.f;
            c0 = __builtin_amdgcn_mfma_f32_16x16x32_bf16(av, bv0, c0, 0, 0, 0);
            c1 = __builtin_amdgcn_mfma_f32_16x16x32_bf16(av, bv1, c1, 0, 0, 0);
            float* ob = on + (size_t)o_g * TV;
            #pragma unroll
            for (int r = 0; r < 4; ++r) {
                const int t = lg * 4 + r;                       // C: row=t, col=v
                ob[t * 25 + l16] = c0[r];
                if (l16 < 9) ob[t * 25 + 16 + l16] = c1[r];
            }
        }
        __syncthreads();   // protect x3b before next quarter's GEMM1 writes
    }
}

extern "C" void kernel_launch(void* const* d_in, const int* in_sizes, int n_in,
                              void* d_out, int out_size, void* d_ws, size_t ws_size,
                              hipStream_t stream) {
    const float* x  = (const float*)d_in[0];
    const float* A  = (const float*)d_in[1];
    const float* w1 = (const float*)d_in[2];
    const float* b1 = (const float*)d_in[3];
    const float* w2 = (const float*)d_in[4];
    const float* b2 = (const float*)d_in[5];
    const float* w3 = (const float*)d_in[6];
    const float* b3 = (const float*)d_in[7];
    const float* w4 = (const float*)d_in[8];
    const float* b4 = (const float*)d_in[9];

    float* out = (float*)d_out;
    float* xm  = (float*)d_ws;                                          // 0.41 MB f32
    unsigned short* dTm = (unsigned short*)(xm + (size_t)N_ * C_ * V_); // N*O*32*32 bf16 (8.4 MB)

    k_mean<<<N_ * C_, 256, 0, stream>>>(x, xm);
    k_dmat<<<dim3(N_, 8), 256, 0, stream>>>(xm, A, w1, b1, w2, b2, w4, b4, dTm);
    k_F<<<dim3(T_ / TC, N_), 512, 0, stream>>>(x, w3, b3, dTm, out);
}

// Round 10
// 83.131 us; speedup vs baseline: 1.0640x; 1.0640x over previous
//
#include <hip/hip_runtime.h>

#define N_ 64
#define C_ 64
#define T_ 256
#define V_ 25
#define R_ 8
#define O_ 64
constexpr int TV = T_ * V_;           // 6400
constexpr float INV_T = 1.0f / (float)T_;
constexpr int TC = 16;                // t's per fused block
constexpr int NPOS = TC * V_;         // 400
constexpr int NT = NPOS / 16;         // 25 MFMA N-tiles
constexpr int DP = 32;                // padded u,v extent of dT in global
constexpr int UPAD = 40;              // u slots per (o,t) row in x3b
constexpr int X3S = 16 * UPAD + 8;    // 648 halfwords per o_local

typedef __attribute__((ext_vector_type(8))) short s8v;   // 8 bf16 = 4 VGPR
typedef __attribute__((ext_vector_type(4))) short s4v;   // 4 bf16
typedef __attribute__((ext_vector_type(4))) float f4v;   // MFMA acc / float4

__device__ __forceinline__ unsigned short f2bf(float f) {   // RNE f32->bf16
    union { float f; unsigned u; } v; v.f = f;
    unsigned r = v.u + 0x7FFFu + ((v.u >> 16) & 1u);
    return (unsigned short)(r >> 16);
}

// -------- k_mean: xm[n][c][v] = mean_t x[n][c][t][v]  (proven ~19us, ~5.5TB/s)
__global__ __launch_bounds__(256) void k_mean(const float* __restrict__ x,
                                              float* __restrict__ xm) {
    __shared__ float part[8 * V_];
    const int bid = blockIdx.x;           // n*C + c
    const int tid = threadIdx.x;
    const float* xp = x + (size_t)bid * TV;
    if (tid < 200) {
        const int vid = tid % V_;
        const int seg = tid / V_;
        float s = 0.f;
        const float* p = xp + seg * 32 * V_ + vid;
        #pragma unroll
        for (int j = 0; j < 32; ++j) s += p[j * V_];
        part[tid] = s;
    }
    __syncthreads();
    if (tid < V_) {
        float s = 0.f;
        #pragma unroll
        for (int k = 0; k < 8; ++k) s += part[k * V_ + tid];
        xm[(size_t)bid * V_ + tid] = s * INV_T;
    }
}

// -------- k_dmat: dT[n][o][v][u] = d(u,v) bf16, zero-padded to 32x32.
__global__ __launch_bounds__(256) void k_dmat(const float* __restrict__ xm,
                                              const float* __restrict__ A,
                                              const float* __restrict__ w1,
                                              const float* __restrict__ b1,
                                              const float* __restrict__ w2,
                                              const float* __restrict__ b2,
                                              const float* __restrict__ w4,
                                              const float* __restrict__ b4,
                                              unsigned short* __restrict__ dT) {
    __shared__ float xms[C_][V_];
    __shared__ float x1s[R_][V_];
    __shared__ float x2s[R_][V_];
    const int n  = blockIdx.x;
    const int og = blockIdx.y * 8;
    const int tid = threadIdx.x;

    for (int i = tid; i < C_ * V_; i += 256)
        xms[i / V_][i % V_] = xm[(size_t)n * C_ * V_ + i];
    __syncthreads();

    for (int i = tid; i < 2 * R_ * V_; i += 256) {
        const int j = i % (R_ * V_);
        const int r = j / V_, v = j % V_;
        const bool first = (i < R_ * V_);
        const float* w = first ? w1 : w2;
        float acc = first ? b1[r] : b2[r];
        #pragma unroll
        for (int c = 0; c < C_; ++c) acc += w[r * C_ + c] * xms[c][v];
        if (first) x1s[r][v] = acc;
        else       x2s[r][v] = acc;
    }
    __syncthreads();

    unsigned short* dn = dT + (size_t)n * O_ * DP * DP;
    for (int p = tid; p < DP * DP; p += 256) {       // p = v*32+u, coalesced in u
        const int v = p >> 5, u = p & 31;
        if (u < V_ && v < V_) {
            float adjr[R_];
            #pragma unroll
            for (int r = 0; r < R_; ++r) adjr[r] = tanhf(x1s[r][u] - x2s[r][v]);
            const float a = A[u * V_ + v];
            #pragma unroll
            for (int oo = 0; oo < 8; ++oo) {
                const int o = og + oo;
                float acc = b4[o];
                #pragma unroll
                for (int r = 0; r < R_; ++r) acc = fmaf(w4[o * R_ + r], adjr[r], acc);
                dn[(size_t)o * DP * DP + p] = f2bf(acc + a);   // ALPHA == 1
            }
        } else {
            #pragma unroll
            for (int oo = 0; oo < 8; ++oo)
                dn[(size_t)(og + oo) * DP * DP + p] = 0;
        }
    }
}

// -------- k_F: stage x->LDS, GEMM1 (MFMA) per o-quarter into x3b,
//          GEMM2 (MFMA) -> LDS outb -> contiguous float4 global writes.
//          512 thr, ~72KB LDS -> 2 blocks/CU.
__global__ __launch_bounds__(512, 4) void k_F(const float* __restrict__ x,
                                              const float* __restrict__ w3,
                                              const float* __restrict__ b3,
                                              const unsigned short* __restrict__ dT,
                                              float* __restrict__ out) {
    // xs: bf16 x-tile [nt][c^swz][16pos]; REUSED after B-frag hoist as the
    //     output staging buffer outb[16][400] f32 (25.6KB of the 51.2KB).
    __shared__ __align__(16) unsigned short xs[NT * 1024];        // 51200 B
    __shared__ __align__(16) unsigned short x3b[16 * X3S];        // 20736 B
    float* outb = (float*)xs;

    const int n    = blockIdx.y;
    const int tc   = blockIdx.x;
    const int tid  = threadIdx.x;
    const int lane = tid & 63;
    const int wave = tid >> 6;      // 0..7
    const int l16  = lane & 15;
    const int lg   = lane >> 4;     // 0..3

    // zero x3b u-pad [24,32) (u=24 rewritten by GEMM1; [25,32) must stay 0)
    if (tid < 256) {
        const int o_l = tid >> 4, t = tid & 15;
        *(s8v*)&x3b[o_l * X3S + t * UPAD + 24] = (s8v)0;   // 16B-aligned
    }

    // ---- stage x chunk: 13 independent float4 loads, FULLY unrolled so all
    //      13 are in flight before the first wait (r9 had unroll 1).
    {
        const float* xb = x + (size_t)n * C_ * TV + tc * NPOS;
        #pragma unroll
        for (int i = 0; i < 13; ++i) {
            const int s = i * 512 + tid;
            if (s < 6400) {
                const int c = s / 100, p4 = s - c * 100;
                const float4 v4 = *(const float4*)(xb + (size_t)c * TV + p4 * 4);
                const int pos = p4 * 4;
                const int pt = pos >> 4;
                s4v pk;
                pk[0] = (short)f2bf(v4.x); pk[1] = (short)f2bf(v4.y);
                pk[2] = (short)f2bf(v4.z); pk[3] = (short)f2bf(v4.w);
                *(s4v*)&xs[pt * 1024 + ((c ^ (pt & 7)) << 4) + (pos & 15)] = pk;
            }
        }
    }
    __syncthreads();

    // ---- hoist this wave's B-frags (reused for all 4 o-quarters); after this
    //      (and the barrier below) xs is dead -> outb may overwrite it.
    s8v bfr[4][2];
    int ts[4], us[4];
    #pragma unroll
    for (int i = 0; i < 4; ++i) {
        const int nt = wave + 8 * i;
        if (nt < NT) {
            const int pos = nt * 16 + l16;
            ts[i] = pos / 25; us[i] = pos - 25 * ts[i];
            const unsigned short* base = &xs[nt * 1024];
            const int sw = nt & 7;
            #pragma unroll
            for (int kh = 0; kh < 2; ++kh) {
                s8v f;
                #pragma unroll
                for (int j = 0; j < 8; ++j) {
                    const int c = kh * 32 + lg * 8 + j;
                    f[j] = (short)base[((c ^ sw) << 4) + l16];   // 2-way max, free
                }
                bfr[i][kh] = f;
            }
        }
    }

    const unsigned short* dn = dT + (size_t)n * O_ * DP * DP;
    float* on = out + (size_t)n * O_ * TV + tc * NPOS;

    #pragma unroll 1
    for (int h = 0; h < 4; ++h) {               // o-quarter: o = h*16 .. h*16+15
        // A-frags for this quarter (w3 L1-resident)
        s8v afr[2];
        #pragma unroll
        for (int kh = 0; kh < 2; ++kh) {
            const float* wp = w3 + (h * 16 + l16) * C_ + kh * 32 + lg * 8;
            s8v f;
            #pragma unroll
            for (int j = 0; j < 8; ++j) f[j] = (short)f2bf(wp[j]);
            afr[kh] = f;
        }
        const f4v b3h = *(const f4v*)(b3 + h * 16 + lg * 4);

        // GEMM1 quarter: x3[o_l][t][u], o_l = lg*4+r
        #pragma unroll
        for (int i = 0; i < 4; ++i) {
            const int nt = wave + 8 * i;
            if (nt < NT) {
                f4v acc = (f4v)0.f;
                acc = __builtin_amdgcn_mfma_f32_16x16x32_bf16(afr[0], bfr[i][0], acc, 0, 0, 0);
                acc = __builtin_amdgcn_mfma_f32_16x16x32_bf16(afr[1], bfr[i][1], acc, 0, 0, 0);
                #pragma unroll
                for (int r = 0; r < 4; ++r)
                    x3b[(lg * 4 + r) * X3S + ts[i] * UPAD + us[i]] = f2bf(acc[r] + b3h[r]);
            }
        }
        __syncthreads();   // B1: x3b ready (also: first iter, xs reads all done)

        // GEMM2 quarter -> outb (LDS), wave owns o_l = wave*2 + {0,1}
        #pragma unroll
        for (int oo = 0; oo < 2; ++oo) {
            const int o_l = wave * 2 + oo;
            const int o_g = h * 16 + o_l;
            const s8v av  = *(const s8v*)&x3b[o_l * X3S + l16 * UPAD + lg * 8]; // b128
            const unsigned short* dp = dn + (size_t)o_g * DP * DP;
            const s8v bv0 = *(const s8v*)(dp + l16 * DP + lg * 8);
            const s8v bv1 = *(const s8v*)(dp + (16 + l16) * DP + lg * 8);
            f4v c0 = (f4v)0.f, c1 = (f4v)0.f;
            c0 = __builtin_amdgcn_mfma_f32_16x16x32_bf16(av, bv0, c0, 0, 0, 0);
            c1 = __builtin_amdgcn_mfma_f32_16x16x32_bf16(av, bv1, c1, 0, 0, 0);
            float* obl = outb + o_l * NPOS;
            #pragma unroll
            for (int r = 0; r < 4; ++r) {
                const int t = lg * 4 + r;                       // C: row=t, col=v
                obl[t * 25 + l16] = c0[r];
                if (l16 < 9) obl[t * 25 + 16 + l16] = c1[r];
            }
        }
        __syncthreads();   // B2: outb complete

        // copy outb -> global: contiguous, aligned float4 (full 64B lines)
        #pragma unroll
        for (int i = 0; i < 4; ++i) {
            const int s = i * 512 + tid;        // s = o_l*100 + p4
            if (s < 1600) {
                const int o_l = s / 100, p4 = s - o_l * 100;
                const f4v val = *(const f4v*)(outb + o_l * NPOS + p4 * 4);
                *(f4v*)(on + (size_t)(h * 16 + o_l) * TV + p4 * 4) = val;
            }
        }
        // no barrier needed here: next GEMM1 touches only x3b; B1 of the next
        // quarter protects outb before its next write.
    }
}

extern "C" void kernel_launch(void* const* d_in, const int* in_sizes, int n_in,
                              void* d_out, int out_size, void* d_ws, size_t ws_size,
                              hipStream_t stream) {
    const float* x  = (const float*)d_in[0];
    const float* A  = (const float*)d_in[1];
    const float* w1 = (const float*)d_in[2];
    const float* b1 = (const float*)d_in[3];
    const float* w2 = (const float*)d_in[4];
    const float* b2 = (const float*)d_in[5];
    const float* w3 = (const float*)d_in[6];
    const float* b3 = (const float*)d_in[7];
    const float* w4 = (const float*)d_in[8];
    const float* b4 = (const float*)d_in[9];

    float* out = (float*)d_out;
    float* xm  = (float*)d_ws;                                          // 0.41 MB f32
    unsigned short* dTm = (unsigned short*)(xm + (size_t)N_ * C_ * V_); // N*O*32*32 bf16 (8.4 MB)

    k_mean<<<N_ * C_, 256, 0, stream>>>(x, xm);
    k_dmat<<<dim3(N_, 8), 256, 0, stream>>>(xm, A, w1, b1, w2, b2, w4, b4, dTm);
    k_F<<<dim3(T_ / TC, N_), 512, 0, stream>>>(x, w3, b3, dTm, out);
}